// Round 3
// baseline (362.624 us; speedup 1.0000x reference)
//
#include <hip/hip_runtime.h>
#include <hip/hip_bf16.h>

typedef unsigned short ushort_t;

#define N_IMG 32
#define C_IN  128
#define C_OUT 256
#define H_SZ  56
#define W_SZ  56
#define HW_SZ (H_SZ * W_SZ)        // 3136
#define K_TOT (C_IN * 9)           // 1152
#define SP_TOT (N_IMG * HW_SZ)     // 100352

typedef __attribute__((ext_vector_type(8))) short bf16x8;
typedef __attribute__((ext_vector_type(4))) float floatx4;

__device__ __forceinline__ ushort_t f2bf(float f) {
  __hip_bfloat16 b = __float2bfloat16(f);
  return *reinterpret_cast<ushort_t*>(&b);
}

// w_q (int32 {-1,0,1}, [co][c][kh][kw]) -> w_t bf16 [co][tap][c]; zero 256B pad page
__global__ void wtrans_kernel(const int* __restrict__ wq, ushort_t* __restrict__ wt,
                              ushort_t* __restrict__ zeros) {
  int tid = threadIdx.x;
  if (blockIdx.x == 0 && tid < 128) zeros[tid] = 0;
  int idx = blockIdx.x * 256 + tid;
  if (idx >= C_OUT * K_TOT) return;
  int co = idx / K_TOT;
  int k  = idx - co * K_TOT;
  int tap = k >> 7;          // k = tap*128 + c
  int c   = k & 127;
  int kh = tap / 3, kw = tap - kh * 3;
  int v = wq[((co * C_IN + c) * 3 + kh) * 3 + kw];
  wt[idx] = f2bf((float)v);
}

// x fp32 NCHW -> x_t bf16 NHWC via 64hw x 64c LDS tiles (conflict-free, see R2).
#define LDT 69
__global__ __launch_bounds__(256) void xtrans_kernel(const float* __restrict__ x,
                                                     ushort_t* __restrict__ xt) {
  __shared__ float tile[64 * LDT];   // 17664 B
  int b = blockIdx.x;                // n*98 + cg*49 + hwg
  int n = b / 98;
  int r = b - n * 98;
  int cg = r / 49;
  int hwg = r - cg * 49;
  int hw0 = hwg * 64, c0 = cg * 64;
  int t = threadIdx.x;
  int cl = t >> 4;                   // 0..15
  int f4 = t & 15;
  const float* xb = x + ((size_t)(n * C_IN + c0) * HW_SZ + hw0);
#pragma unroll
  for (int p = 0; p < 4; ++p) {
    int c = p * 16 + cl;
    float4 v = *(const float4*)(xb + (size_t)c * HW_SZ + f4 * 4);
    float* dst = &tile[c * LDT + f4 * 4];
    dst[0] = v.x; dst[1] = v.y; dst[2] = v.z; dst[3] = v.w;
  }
  __syncthreads();
  int cp  = t & 31;                  // channel pair
  int hwl = t >> 5;                  // 0..7
  ushort_t* ob = xt + (size_t)(n * HW_SZ + hw0) * C_IN + c0;
#pragma unroll
  for (int p = 0; p < 8; ++p) {
    int hw = p * 8 + hwl;
    unsigned int u = (unsigned int)f2bf(tile[(2 * cp) * LDT + hw]) |
                     ((unsigned int)f2bf(tile[(2 * cp + 1) * LDT + hw]) << 16);
    *(unsigned int*)&ob[(size_t)hw * C_IN + 2 * cp] = u;
  }
}

// LDS-free implicit-GEMM conv. Both MFMA operands are fragment-loaded directly
// from global (16B/lane contiguous in k): no staging, no barriers, no vmcnt(0)
// drains — the compiler software-pipelines global_load_dwordx4 <-> MFMA across
// the fully unrolled 36 k-steps (AITER-style fine-grained vmcnt).
__global__ __launch_bounds__(256) void bitconv_kernel(
    const ushort_t* __restrict__ wt, const ushort_t* __restrict__ xt,
    const ushort_t* __restrict__ zeros,
    const float* __restrict__ s, const float* __restrict__ bias,
    float* __restrict__ out) {
  // XCD swizzle: co-pair (same sp tile) lands on same XCD under round-robin.
  int d = blockIdx.x;
  int sp_idx = (d >> 4) * 8 + (d & 7);
  int co0 = ((d >> 3) & 1) * 128;
  int sp0 = sp_idx * 128;

  int tid  = threadIdx.x;
  int lane = tid & 63;
  int wid  = tid >> 6;
  int l15  = lane & 15;
  int quad = lane >> 4;
  int wave_m = (wid >> 1) * 64;
  int wave_n = (wid & 1) * 64;

  // A fragment bases: lane row = m, quad*8 = k-chunk. Per-step k offset is a
  // compile-time immediate (tap*128 + ksub*32 elements, max 2240 B < 4 KiB).
  const ushort_t* a_base[4];
#pragma unroll
  for (int mi = 0; mi < 4; ++mi)
    a_base[mi] = wt + (size_t)(co0 + wave_m + mi * 16 + l15) * K_TOT + quad * 8;

  // B columns: lane col = sp; decompose once.
  int bh[4], bw[4];
  const ushort_t* b_img[4];
#pragma unroll
  for (int ni = 0; ni < 4; ++ni) {
    int sp   = sp0 + wave_n + ni * 16 + l15;
    int nimg = sp / HW_SZ;
    int rem  = sp - nimg * HW_SZ;
    bh[ni] = rem / W_SZ;
    bw[ni] = rem - bh[ni] * W_SZ;
    b_img[ni] = xt + (size_t)nimg * HW_SZ * C_IN;
  }

  floatx4 acc[4][4];
#pragma unroll
  for (int mi = 0; mi < 4; ++mi)
#pragma unroll
    for (int ni = 0; ni < 4; ++ni)
      acc[mi][ni] = (floatx4){0.f, 0.f, 0.f, 0.f};

#pragma unroll
  for (int tap = 0; tap < 9; ++tap) {
    const int dh = tap / 3 - 1;
    const int dw = tap % 3 - 1;
    const ushort_t* bptr[4];
#pragma unroll
    for (int ni = 0; ni < 4; ++ni) {
      int hh2 = bh[ni] + dh, ww2 = bw[ni] + dw;
      bool valid = (hh2 >= 0) & (hh2 < H_SZ) & (ww2 >= 0) & (ww2 < W_SZ);
      bptr[ni] = valid ? (b_img[ni] + (size_t)(hh2 * W_SZ + ww2) * C_IN + quad * 8)
                       : (zeros + quad * 8);
    }
#pragma unroll
    for (int ksub = 0; ksub < 4; ++ksub) {
      const int k0 = tap * C_IN + ksub * 32;
      bf16x8 af[4], bfv[4];
#pragma unroll
      for (int mi = 0; mi < 4; ++mi)
        af[mi] = *(const bf16x8*)(a_base[mi] + k0);
#pragma unroll
      for (int ni = 0; ni < 4; ++ni)
        bfv[ni] = *(const bf16x8*)(bptr[ni] + ksub * 32);
#pragma unroll
      for (int mi = 0; mi < 4; ++mi)
#pragma unroll
        for (int ni = 0; ni < 4; ++ni)
          acc[mi][ni] = __builtin_amdgcn_mfma_f32_16x16x32_bf16(
              af[mi], bfv[ni], acc[mi][ni], 0, 0, 0);
    }
  }

  // Epilogue: y = acc*s[co] + bias[co]; C/D layout col(sp)=lane&15, row(co)=quad*4+reg
  int spl_[4], nimg_[4];
#pragma unroll
  for (int ni = 0; ni < 4; ++ni) {
    int sp = sp0 + wave_n + ni * 16 + l15;
    int nimg = sp / HW_SZ;
    nimg_[ni] = nimg;
    spl_[ni]  = sp - nimg * HW_SZ;
  }
#pragma unroll
  for (int mi = 0; mi < 4; ++mi) {
#pragma unroll
    for (int r = 0; r < 4; ++r) {
      int co = co0 + wave_m + mi * 16 + quad * 4 + r;
      float sv = s[co];
      float bv = bias[co];
#pragma unroll
      for (int ni = 0; ni < 4; ++ni) {
        out[((size_t)nimg_[ni] * C_OUT + co) * HW_SZ + spl_[ni]] =
            acc[mi][ni][r] * sv + bv;
      }
    }
  }
}

extern "C" void kernel_launch(void* const* d_in, const int* in_sizes, int n_in,
                              void* d_out, int out_size, void* d_ws, size_t ws_size,
                              hipStream_t stream) {
  const float* x    = (const float*)d_in[0];
  const int*   wq   = (const int*)d_in[1];
  const float* s    = (const float*)d_in[2];
  const float* bias = (const float*)d_in[3];
  float* out = (float*)d_out;

  char* ws = (char*)d_ws;
  ushort_t* zeros = (ushort_t*)ws;                       // 256 B zero page
  ushort_t* wt    = (ushort_t*)(ws + 256);               // 589,824 B
  ushort_t* xt    = (ushort_t*)(ws + 590080);            // 25,690,112 B

  hipLaunchKernelGGL(wtrans_kernel, dim3((C_OUT * K_TOT) / 256), dim3(256), 0, stream,
                     wq, wt, zeros);
  hipLaunchKernelGGL(xtrans_kernel, dim3(N_IMG * 98), dim3(256), 0, stream, x, xt);
  hipLaunchKernelGGL(bitconv_kernel, dim3((C_OUT / 128) * (SP_TOT / 128)), dim3(256),
                     0, stream, wt, xt, zeros, s, bias, out);
}

// Round 4
// 228.151 us; speedup vs baseline: 1.5894x; 1.5894x over previous
//
#include <hip/hip_runtime.h>
#include <hip/hip_bf16.h>

typedef unsigned short ushort_t;

#define N_IMG 32
#define C_IN  128
#define C_OUT 256
#define H_SZ  56
#define W_SZ  56
#define HW_SZ (H_SZ * W_SZ)        // 3136
#define K_TOT (C_IN * 9)           // 1152
#define WP 64                      // padded width  (w' = w+1, zeros at 0,57..63)
#define HP 58                      // padded height (h1 = h+1, zeros at 0,57)
#define ROW_E (WP * C_IN)          // 8192 elements per padded (n,h1) slab

typedef __attribute__((ext_vector_type(8))) short bf16x8;
typedef __attribute__((ext_vector_type(4))) float floatx4;

__device__ __forceinline__ void gl_lds16(const ushort_t* g, ushort_t* l) {
  __builtin_amdgcn_global_load_lds(
      (const __attribute__((address_space(1))) void*)g,
      (__attribute__((address_space(3))) void*)l, 16, 0, 0);
}

__device__ __forceinline__ ushort_t f2bf(float f) {
  __hip_bfloat16 b = __float2bfloat16(f);
  return *reinterpret_cast<ushort_t*>(&b);
}

// w_q (int32 {-1,0,1}, [co][c][kh][kw]) -> w_t bf16 [co][tap*128+c]
__global__ void wtrans_kernel(const int* __restrict__ wq, ushort_t* __restrict__ wt) {
  int idx = blockIdx.x * 256 + threadIdx.x;
  if (idx >= C_OUT * K_TOT) return;
  int co = idx / K_TOT;
  int k  = idx - co * K_TOT;
  int tap = k >> 7;
  int c   = k & 127;
  int kh = tap / 3, kw = tap - kh * 3;
  int v = wq[((co * C_IN + c) * 3 + kh) * 3 + kw];
  wt[idx] = f2bf((float)v);
}

// x fp32 NCHW -> xp bf16 padded-NHWC: xp[n][h1][w'][c], h1=h+1 (0,57 zero),
// w'=w+1 (0,57..63 zero), +1 slack row at the end (OOB spill for discarded cols).
__global__ __launch_bounds__(256) void xpad_kernel(const float* __restrict__ x,
                                                   ushort_t* __restrict__ xp) {
  int b = blockIdx.x;                 // 0..N_IMG*HP (last = slack row)
  int t = threadIdx.x;
  ushort_t* row = xp + (size_t)b * ROW_E;
  int n = b / HP;
  int h1 = b - n * HP;
  if (b >= N_IMG * HP || h1 == 0 || h1 == HP - 1) {
    uint4 z = {0u, 0u, 0u, 0u};
    uint4* r4 = (uint4*)row;          // 16384 B = 1024 uint4
#pragma unroll
    for (int i = 0; i < 4; ++i) r4[i * 256 + t] = z;
    return;
  }
  __shared__ float tile[C_IN * 57];   // stride 57: store-phase 4-way max (free-ish)
  int h = h1 - 1;
  const float* xb = x + (size_t)n * C_IN * HW_SZ + h * W_SZ;
#pragma unroll
  for (int i = 0; i < 7; ++i) {
    int idx = i * 256 + t;            // 0..1791 = 128 c * 14 float4
    int c = idx / 14, f = idx - c * 14;
    float4 v = *(const float4*)(xb + (size_t)c * HW_SZ + f * 4);
    float* dst = &tile[c * 57 + f * 4];
    dst[0] = v.x; dst[1] = v.y; dst[2] = v.z; dst[3] = v.w;
  }
  __syncthreads();
  unsigned int* r32 = (unsigned int*)row;
#pragma unroll
  for (int i = 0; i < 16; ++i) {
    int idx = i * 256 + t;            // 0..4095 = 64 w' * 64 cpair
    int wp = idx >> 6, cp = idx & 63;
    unsigned int u = 0;
    if (wp >= 1 && wp <= W_SZ) {
      int w = wp - 1;
      u = (unsigned int)f2bf(tile[(2 * cp) * 57 + w]) |
          ((unsigned int)f2bf(tile[(2 * cp + 1) * 57 + w]) << 16);
    }
    r32[wp * 64 + cp] = u;            // 256 B contiguous per w'
  }
}

// Implicit GEMM on padded layout: C[co][sp'] over sp' = (n,h-pair,w' 0..63).
// All B staging addresses are one per-lane base + uniform (tap,c0) offset —
// no bounds checks, no selects, regular stride-256B instruction footprints.
__global__ __launch_bounds__(256) void bitconv_kernel(
    const ushort_t* __restrict__ wt, const ushort_t* __restrict__ xp,
    const float* __restrict__ s, const float* __restrict__ bias,
    float* __restrict__ out) {
  __shared__ ushort_t As[128 * 32];   // 8 KB [co_local][c 32]
  __shared__ ushort_t Bs[128 * 32];   // 8 KB [sp_local][c 32]

  // XCD swizzle: XCD = d&7 gets contiguous sp range (xp slice ~3.8MB -> L2);
  // co-pair of one sp tile adjacent in dispatch on the same XCD.
  int d = blockIdx.x;                 // 1792 = 8 XCD * 2 co * 112 sp
  int xcd = d & 7;
  int r   = d >> 3;                   // 0..223
  int co0 = (r & 1) * 128;
  int sp_tile = xcd * 112 + (r >> 1); // 0..895
  int nh0 = sp_tile * 2;
  int n  = nh0 / H_SZ;
  int hh = nh0 - n * H_SZ;            // even; tile rows hh, hh+1

  int tid  = threadIdx.x;
  int lane = tid & 63;
  int wid  = tid >> 6;
  int l15  = lane & 15;
  int quad = lane >> 4;
  int wave_m = (wid >> 1) * 64;
  int wave_n = (wid & 1) * 64;
  int lrow = lane >> 2;               // 0..15
  int lchk = (lane & 3) * 8;          // element offset of 16B chunk

  // Staging: wave wid covers rows [wid*32, wid*32+32) of both A and B,
  // two 16-row groups each; per-lane source = row(lane>>2), chunk(lane&3)
  // -> LDS dest base + lane*16 exactly.
  const ushort_t* a_src[2];
  const ushort_t* b_src[2];
  ushort_t* a_dst[2];
  ushort_t* b_dst[2];
#pragma unroll
  for (int g = 0; g < 2; ++g) {
    int rrow = wid * 32 + g * 16 + lrow;        // 0..127
    a_src[g] = wt + (size_t)(co0 + rrow) * K_TOT + lchk;
    int hrow = rrow >> 6, wpp = (rrow & 63) + 1;
    b_src[g] = xp + (size_t)((n * HP + hh + 1 + hrow) * WP + wpp) * C_IN + lchk;
    a_dst[g] = &As[(wid * 32 + g * 16) * 32];
    b_dst[g] = &Bs[(wid * 32 + g * 16) * 32];
  }

  floatx4 acc[4][4];
#pragma unroll
  for (int mi = 0; mi < 4; ++mi)
#pragma unroll
    for (int ni = 0; ni < 4; ++ni)
      acc[mi][ni] = (floatx4){0.f, 0.f, 0.f, 0.f};

  for (int tap = 0; tap < 9; ++tap) {
    int dh = tap / 3 - 1;
    int dw = tap - (dh + 1) * 3 - 1;
    int boff = dh * (WP * C_IN) + dw * C_IN;    // uniform B offset (elements)
    int aoff = tap * C_IN;                      // uniform A offset
#pragma unroll
    for (int c0 = 0; c0 < C_IN; c0 += 32) {
#pragma unroll
      for (int g = 0; g < 2; ++g) {
        gl_lds16(a_src[g] + aoff + c0, a_dst[g]);
        gl_lds16(b_src[g] + boff + c0, b_dst[g]);
      }
      __syncthreads();
      bf16x8 af[4], bfv[4];
#pragma unroll
      for (int mi = 0; mi < 4; ++mi)
        af[mi] = *(const bf16x8*)&As[(wave_m + mi * 16 + l15) * 32 + quad * 8];
#pragma unroll
      for (int ni = 0; ni < 4; ++ni)
        bfv[ni] = *(const bf16x8*)&Bs[(wave_n + ni * 16 + l15) * 32 + quad * 8];
#pragma unroll
      for (int mi = 0; mi < 4; ++mi)
#pragma unroll
        for (int ni = 0; ni < 4; ++ni)
          acc[mi][ni] = __builtin_amdgcn_mfma_f32_16x16x32_bf16(
              af[mi], bfv[ni], acc[mi][ni], 0, 0, 0);
      __syncthreads();
    }
  }

  // Epilogue: col(sp)=l15, row(co)=quad*4+reg; w'' = ni*16+l15, h_row = wid&1.
  int h_out = hh + (wid & 1);
#pragma unroll
  for (int mi = 0; mi < 4; ++mi) {
#pragma unroll
    for (int rg = 0; rg < 4; ++rg) {
      int co = co0 + wave_m + mi * 16 + quad * 4 + rg;
      float sv = s[co];
      float bv = bias[co];
      float* ob = out + (size_t)(n * C_OUT + co) * HW_SZ + h_out * W_SZ;
#pragma unroll
      for (int ni = 0; ni < 4; ++ni) {
        int wpp = ni * 16 + l15;      // 0..63 padded col
        if (wpp < W_SZ)
          ob[wpp] = acc[mi][ni][rg] * sv + bv;
      }
    }
  }
}

extern "C" void kernel_launch(void* const* d_in, const int* in_sizes, int n_in,
                              void* d_out, int out_size, void* d_ws, size_t ws_size,
                              hipStream_t stream) {
  const float* x    = (const float*)d_in[0];
  const int*   wq   = (const int*)d_in[1];
  const float* s    = (const float*)d_in[2];
  const float* bias = (const float*)d_in[3];
  float* out = (float*)d_out;

  char* ws = (char*)d_ws;
  ushort_t* wt = (ushort_t*)ws;                          // 589,824 B
  ushort_t* xp = (ushort_t*)(ws + 589824);               // (32*58+1)*16384 B ≈ 30.4 MB

  hipLaunchKernelGGL(wtrans_kernel, dim3((C_OUT * K_TOT) / 256), dim3(256), 0, stream,
                     wq, wt);
  hipLaunchKernelGGL(xpad_kernel, dim3(N_IMG * HP + 1), dim3(256), 0, stream, x, xp);
  hipLaunchKernelGGL(bitconv_kernel, dim3(1792), dim3(256), 0, stream,
                     wt, xp, s, bias, out);
}